// Round 12
// baseline (150.818 us; speedup 1.0000x reference)
//
#include <hip/hip_runtime.h>
#include <hip/hip_bf16.h>
#include <hip/hip_fp16.h>

// Problem constants
#define BB 8
#define CIN 128
#define HH 48
#define WW 48
#define HW 2304          // 48*48
#define KK 9
#define COUT 256
#define KC 1152          // K*CIN
#define MM 18432         // B*HW
#define MT 32            // M-tile rows per block (fused kernel)
#define SFP 136          // feats LDS row stride in elements (16B-aligned)
#define NP 5             // chunk pairs: ceil(9/2)

// Barrier that waits only on LDS ops (ds_write visibility), leaving global
// loads in flight across the barrier. Correct: s_feat is double-buffered.
#define LIGHT_BARRIER() asm volatile("s_waitcnt lgkmcnt(0)\n\ts_barrier" ::: "memory")

typedef short bf16x8_t __attribute__((ext_vector_type(8)));
typedef float f32x16_t __attribute__((ext_vector_type(16)));
typedef float f32x4_t  __attribute__((ext_vector_type(4)));
typedef unsigned int uint4_t __attribute__((ext_vector_type(4)));

static __device__ __forceinline__ float b2f(short u) {
    union { unsigned int i; float f; } c;
    c.i = ((unsigned int)(unsigned short)u) << 16;
    return c.f;
}

// ---------------------------------------------------------------------------
// PREP kernel: transpose (blocks 0..575), pack_wu (576..719),
// params MLP (720..1295; 4 positions per block, one wave each).
// ---------------------------------------------------------------------------
__global__ __launch_bounds__(256) void prep_kernel(
    const float* __restrict__ x, __hip_bfloat16* __restrict__ xT,
    const float* __restrict__ Wu, bf16x8_t* __restrict__ Bp,
    const float* __restrict__ W1, const float* __restrict__ b1,
    const float* __restrict__ W2, const float* __restrict__ b2,
    float* __restrict__ means, float* __restrict__ sigmas, int* __restrict__ fls)
{
    int bid = blockIdx.x;
    int t = threadIdx.x;

    if (bid < 576) {
        // ---- transpose x (b,c,h,w) fp32 -> xT (b,hw,c) bf16
        __shared__ float tile[64][65];
        int ij0 = (bid % 36) * 64;
        int c0  = ((bid / 36) % 2) * 64;
        int b   = bid / 72;
        int ijl = t & 63, cl = t >> 6;
        #pragma unroll
        for (int i = 0; i < 16; i++) {
            int cc = i*4 + cl;
            tile[cc][ijl] = x[(size_t)(b*CIN + c0 + cc) * HW + ij0 + ijl];
        }
        __syncthreads();
        int cl2 = t & 63, ijl2 = t >> 6;
        #pragma unroll
        for (int i = 0; i < 16; i++) {
            int ij = i*4 + ijl2;
            xT[(size_t)(b*HW + ij0 + ij) * CIN + c0 + cl2] = __float2bfloat16(tile[cl2][ij]);
        }
    } else if (bid < 720) {
        // ---- pack Wu fp32 -> bf16 fragments
        // Bp[(g*72+s)*64+lane]: Wu[g*32 + (lane&31)][s*16 + (lane>>5)*8 + j]
        int idx = (bid - 576) * 256 + t;          // 0 .. 36863
        int lane = idx & 63;
        int rest = idx >> 6;
        int s = rest % 72, g = rest / 72;
        int r = lane & 31, qq = lane >> 5;
        const float* src = Wu + (size_t)(g*32 + r) * KC + s*16 + qq*8;
        union { bf16x8_t v; __hip_bfloat16 h[8]; } o;
        #pragma unroll
        for (int j = 0; j < 8; j++) o.h[j] = __float2bfloat16(src[j]);
        Bp[idx] = o.v;
    } else {
        // ---- params MLP, wave-parallel fp64. One wave per position.
        int wave = t >> 6, lane = t & 63;
        int p = (bid - 720) * 4 + wave;           // 0..2303
        int iy = p / WW, ix = p % WW;
        float ryf = (float)iy / 47.0f;
        float rxf = (float)ix / 47.0f;
        double ry = (double)ryf, rx = (double)rxf;

        double h[8];
        #pragma unroll
        for (int jj = 0; jj < 8; jj++) {
            int j = lane*8 + jj;
            double v = ry * (double)W1[j*2+0] + rx * (double)W1[j*2+1] + (double)b1[j];
            h[jj] = v > 0.0 ? v : 0.0;
        }
        double par[27];
        #pragma unroll
        for (int o = 0; o < 27; o++) {
            const float4* w4 = (const float4*)(W2 + (size_t)o*512 + lane*8);
            float4 wa = w4[0], wb = w4[1];
            double s = (double)wa.x*h[0] + (double)wa.y*h[1]
                     + (double)wa.z*h[2] + (double)wa.w*h[3]
                     + (double)wb.x*h[4] + (double)wb.y*h[5]
                     + (double)wb.z*h[6] + (double)wb.w*h[7];
            par[o] = s;
        }
        #pragma unroll
        for (int o = 0; o < 27; o++) {
            #pragma unroll
            for (int d = 1; d < 64; d <<= 1)
                par[o] += __shfl_xor(par[o], d, 64);
            par[o] += (double)b2[o];
        }
        if (lane < KK) {
            int k = lane;
            double scy = ry * 0.9999 + 5e-05;
            double scx = rx * 0.9999 + 5e-05;
            double midy = log(scy / (1.0 - scy));
            double midx = log(scx / (1.0 - scx));
            double zy = midy + 0.1 * par[2*k+0];
            double zx = midx + 0.1 * par[2*k+1];
            double my = 47.0 / (1.0 + exp(-zy));
            double mx = 47.0 / (1.0 + exp(-zx));
            double sr = par[18 + k] + 2.0;
            double sp = (sr > 0.0 ? sr : 0.0) + log1p(exp(-fabs(sr)));
            double sg = (sp + 0.05) * 48.0 * 0.05;
            means[(p*KK + k)*2 + 0] = (float)my;
            means[(p*KK + k)*2 + 1] = (float)mx;
            sigmas[p*KK + k] = (float)sg;
            fls[(p*KK + k)*2 + 0] = (int)floor(my);
            fls[(p*KK + k)*2 + 1] = (int)floor(mx);
        }
    }
}

// ---------------------------------------------------------------------------
// TAPS kernel: one thread per (bij, k) computes 8 packed tap descriptors
// ((lin<<16)|fp16(weight)) -> Tg[bij*72 + k*8 + v].  Coalesced gints/roff
// streaming; dup-kill + normalize here, OFF the fused critical path.
// ---------------------------------------------------------------------------
__global__ __launch_bounds__(256) void taps_kernel(
    const float* __restrict__ means, const float* __restrict__ sigmas,
    const int* __restrict__ fls, const int* __restrict__ gints,
    const int* __restrict__ roff, unsigned int* __restrict__ Tg)
{
    int idx = blockIdx.x * 256 + threadIdx.x;    // 0 .. 165887
    int bij = idx / KK;
    int k   = idx - bij * KK;
    int ij  = bij % HW;

    int fy = fls[(ij*KK + k)*2 + 0];
    int fx = fls[(ij*KK + k)*2 + 1];
    float my = means[(ij*KK + k)*2 + 0];
    float mx = means[(ij*KK + k)*2 + 1];
    float sg = sigmas[ij*KK + k];

    int lins[8]; float ws[8];
    #pragma unroll
    for (int v = 0; v < 8; v++) {
        int iy, ix;
        if (v < 4) {
            iy = fy + (v >> 1); ix = fx + (v & 1);
        } else if (v < 6) {
            int base = ((bij*KK + k)*2 + (v - 4)) * 2;
            iy = gints[base]; ix = gints[base + 1];
        } else {
            int base = ((bij*KK + k)*2 + (v - 6)) * 2;
            iy = fy + roff[base] - 6; ix = fx + roff[base + 1] - 6;
        }
        iy = ((iy % HH) + HH) % HH;
        ix = ((ix % WW) + WW) % WW;
        lins[v] = iy * WW + ix;
        float dy = ((float)iy - my) / sg;
        float dx = ((float)ix - mx) / sg;
        ws[v] = expf(-0.5f * (dy*dy + dx*dx));
    }
    #pragma unroll
    for (int v = 1; v < 8; v++) {
        bool dup = false;
        #pragma unroll
        for (int u = 0; u < 8; u++) if (u < v) dup = dup || (lins[u] == lins[v]);
        if (dup) ws[v] = 0.0f;
    }
    float sum = 0.0f;
    #pragma unroll
    for (int v = 0; v < 8; v++) sum += ws[v];
    float inv = 1.0f / sum;
    uint4_t o0, o1;
    #pragma unroll
    for (int v = 0; v < 4; v++) {
        unsigned short hb = __half_as_ushort(__float2half(ws[v] * inv));
        o0[v] = ((unsigned int)lins[v] << 16) | (unsigned int)hb;
        unsigned short hb2 = __half_as_ushort(__float2half(ws[4+v] * inv));
        o1[v] = ((unsigned int)lins[4+v] << 16) | (unsigned int)hb2;
    }
    uint4_t* dst = (uint4_t*)(Tg + (size_t)bij*72 + k*8);
    dst[0] = o0;
    dst[1] = o1;
}

// ---------------------------------------------------------------------------
// FUSED gather + GEMM (R12): R10 chunk-pair structure, setup REMOVED.
// 512 threads: gather covers TWO chunks/phase (cpart = t>>8, row = (t>>3)&31,
// 16-ch base = (t&7)*16); descriptors read per chunk as two uint4 from Tg.
// 5 light barriers; XCD swizzle (b = bid&7).
// ---------------------------------------------------------------------------
__global__ __launch_bounds__(512, 4) void fused_kernel(
    const unsigned int* __restrict__ Tg, const short* __restrict__ xT,
    const bf16x8_t* __restrict__ Bp, const float* __restrict__ bu,
    float* __restrict__ out)
{
    __shared__ __align__(16) short s_feat[2][2][MT*SFP];    // 34816 B

    int t = threadIdx.x;
    // XCD swizzle: each XCD streams one batch image (~L2-resident)
    int b   = blockIdx.x & 7;
    int grp = blockIdx.x >> 3;          // 0..71 within batch
    int ij0 = grp * MT;

    const short* xb = xT + (size_t)b * (HW * CIN);
    int lane = t & 63, wave = t >> 6;
    int r = lane & 31, q = lane >> 5;
    int cpart = t >> 8;                 // chunk half 0/1
    int grow = (t >> 3) & 31;           // row 0..31
    int gc0 = (t & 7) << 4;             // 16-ch base

    const unsigned int* tb = Tg + ((size_t)(b*HW + ij0) + grow) * 72;

    f32x16_t acc = {};

    for (int p = 0; p < NP; p++) {
        int kg = 2*p + cpart;
        // ---- gather phase: this thread's chunk kg, 16 channels, 8 taps
        if (kg < KK) {
            const uint4_t* tp = (const uint4_t*)(tb + kg*8);
            uint4_t e0 = tp[0], e1 = tp[1];
            unsigned int e[8] = {e0[0], e0[1], e0[2], e0[3],
                                 e1[0], e1[1], e1[2], e1[3]};
            // issue all 16 tap loads before any use
            bf16x8_t d0[8], d1[8];
            #pragma unroll
            for (int v = 0; v < 8; v++) {
                const bf16x8_t* sp = (const bf16x8_t*)(xb + (size_t)(e[v] >> 16) * CIN + gc0);
                d0[v] = sp[0];
                d1[v] = sp[1];
            }
            float a0[16];
            #pragma unroll
            for (int j = 0; j < 16; j++) a0[j] = 0.0f;
            #pragma unroll
            for (int v = 0; v < 8; v++) {
                float w = __half2float(__ushort_as_half((unsigned short)(e[v] & 0xffffu)));
                #pragma unroll
                for (int j = 0; j < 8; j++) {
                    a0[j]   += w * b2f(d0[v][j]);
                    a0[8+j] += w * b2f(d1[v][j]);
                }
            }
            union { bf16x8_t v8; __hip_bfloat16 hh[8]; } o0, o1;
            #pragma unroll
            for (int j = 0; j < 8; j++) {
                o0.hh[j] = __float2bfloat16(a0[j]);
                o1.hh[j] = __float2bfloat16(a0[8+j]);
            }
            bf16x8_t* fd = (bf16x8_t*)(&s_feat[p & 1][cpart][grow*SFP + gc0]);
            fd[0] = o0.v8;
            fd[1] = o1.v8;
        }
        // ---- LDS-only barrier (global loads stay in flight)
        LIGHT_BARRIER();
        // ---- MFMA: both chunks of the pair
        #pragma unroll
        for (int cc = 0; cc < 2; cc++) {
            int k = 2*p + cc;
            if (k < KK) {
                const short* fb = s_feat[p & 1][cc];
                int base = (wave*72 + k*8)*64 + lane;
                #pragma unroll
                for (int si = 0; si < 8; si++) {
                    bf16x8_t Bf = Bp[base + si*64];
                    bf16x8_t a = *(const bf16x8_t*)(fb + r*SFP + si*16 + q*8);
                    acc = __builtin_amdgcn_mfma_f32_32x32x16_bf16(a, Bf, acc, 0, 0, 0);
                }
            }
        }
        // pair-buf (p+2)&1 == p&1 only rewritten after barrier p+1: safe.
    }

    // ---- epilogue: C col = r (n), row = (reg&3)+8*(reg>>2)+4*q
    int n = wave*32 + r;
    float bv = bu[n];
    float* oc = out + ((size_t)b * COUT + n) * HW + ij0;
    #pragma unroll
    for (int g4 = 0; g4 < 4; g4++) {
        f32x4_t vv;
        vv[0] = acc[g4*4+0] + bv;
        vv[1] = acc[g4*4+1] + bv;
        vv[2] = acc[g4*4+2] + bv;
        vv[3] = acc[g4*4+3] + bv;
        *(f32x4_t*)(oc + g4*8 + q*4) = vv;
    }
}

// ---------------------------------------------------------------------------
extern "C" void kernel_launch(void* const* d_in, const int* in_sizes, int n_in,
                              void* d_out, int out_size, void* d_ws, size_t ws_size,
                              hipStream_t stream)
{
    const float* x   = (const float*)d_in[0];
    const float* W1  = (const float*)d_in[1];
    const float* b1  = (const float*)d_in[2];
    const float* W2  = (const float*)d_in[3];
    const float* b2  = (const float*)d_in[4];
    const float* Wu  = (const float*)d_in[5];
    const float* bu  = (const float*)d_in[6];
    const int* gints = (const int*)d_in[7];
    const int* roff  = (const int*)d_in[8];
    float* out = (float*)d_out;

    char* ws = (char*)d_ws;
    float* ws_means  = (float*)(ws + 0);                    // 2304*18 fp32
    float* ws_sigma  = (float*)(ws + 165888);               // 2304*9  fp32
    int*   ws_fl     = (int*  )(ws + 248832);               // 2304*18 int
    short* ws_xT     = (short*)(ws + 414720);               // 8*2304*128 bf16
    bf16x8_t* ws_bp  = (bf16x8_t*)(ws + 5133312);           // packed Wu bf16
    unsigned int* ws_tg = (unsigned int*)(ws + 5723136);    // 18432*72 uint (5.3 MB)

    prep_kernel<<<1296, 256, 0, stream>>>(x, (__hip_bfloat16*)ws_xT, Wu, ws_bp,
                                          W1, b1, W2, b2,
                                          ws_means, ws_sigma, ws_fl);
    taps_kernel<<<648, 256, 0, stream>>>(ws_means, ws_sigma, ws_fl, gints, roff,
                                         ws_tg);
    fused_kernel<<<MM/MT, 512, 0, stream>>>(ws_tg, ws_xT, ws_bp, bu, out);
}

// Round 13
// 146.356 us; speedup vs baseline: 1.0305x; 1.0305x over previous
//
#include <hip/hip_runtime.h>
#include <hip/hip_bf16.h>
#include <hip/hip_fp16.h>

// Problem constants
#define BB 8
#define CIN 128
#define HH 48
#define WW 48
#define HW 2304          // 48*48
#define KK 9
#define COUT 256
#define KC 1152          // K*CIN
#define MM 18432         // B*HW
#define MT 32            // M-tile rows per block (fused kernel)
#define SFP 136          // feats LDS row stride in elements (16B-aligned)

// Barrier that waits only on LDS ops (ds_write visibility), leaving global
// loads in flight across the barrier. Correct: s_feat is double-buffered.
#define LIGHT_BARRIER() asm volatile("s_waitcnt lgkmcnt(0)\n\ts_barrier" ::: "memory")

typedef short bf16x8_t __attribute__((ext_vector_type(8)));
typedef float f32x16_t __attribute__((ext_vector_type(16)));
typedef float f32x4_t  __attribute__((ext_vector_type(4)));

static __device__ __forceinline__ float b2f(short u) {
    union { unsigned int i; float f; } c;
    c.i = ((unsigned int)(unsigned short)u) << 16;
    return c.f;
}

// ---------------------------------------------------------------------------
// PREP kernel: transpose (blocks 0..575), pack_wu (576..719),
// params MLP (720..1295; 4 positions per block, one wave each).
// ---------------------------------------------------------------------------
__global__ __launch_bounds__(256) void prep_kernel(
    const float* __restrict__ x, __hip_bfloat16* __restrict__ xT,
    const float* __restrict__ Wu, bf16x8_t* __restrict__ Bp,
    const float* __restrict__ W1, const float* __restrict__ b1,
    const float* __restrict__ W2, const float* __restrict__ b2,
    float* __restrict__ means, float* __restrict__ sigmas, int* __restrict__ fls)
{
    int bid = blockIdx.x;
    int t = threadIdx.x;

    if (bid < 576) {
        // ---- transpose x (b,c,h,w) fp32 -> xT (b,hw,c) bf16
        __shared__ float tile[64][65];
        int ij0 = (bid % 36) * 64;
        int c0  = ((bid / 36) % 2) * 64;
        int b   = bid / 72;
        int ijl = t & 63, cl = t >> 6;
        #pragma unroll
        for (int i = 0; i < 16; i++) {
            int cc = i*4 + cl;
            tile[cc][ijl] = x[(size_t)(b*CIN + c0 + cc) * HW + ij0 + ijl];
        }
        __syncthreads();
        int cl2 = t & 63, ijl2 = t >> 6;
        #pragma unroll
        for (int i = 0; i < 16; i++) {
            int ij = i*4 + ijl2;
            xT[(size_t)(b*HW + ij0 + ij) * CIN + c0 + cl2] = __float2bfloat16(tile[cl2][ij]);
        }
    } else if (bid < 720) {
        // ---- pack Wu fp32 -> bf16 fragments
        // Bp[(g*72+s)*64+lane]: Wu[g*32 + (lane&31)][s*16 + (lane>>5)*8 + j]
        int idx = (bid - 576) * 256 + t;          // 0 .. 36863
        int lane = idx & 63;
        int rest = idx >> 6;
        int s = rest % 72, g = rest / 72;
        int r = lane & 31, qq = lane >> 5;
        const float* src = Wu + (size_t)(g*32 + r) * KC + s*16 + qq*8;
        union { bf16x8_t v; __hip_bfloat16 h[8]; } o;
        #pragma unroll
        for (int j = 0; j < 8; j++) o.h[j] = __float2bfloat16(src[j]);
        Bp[idx] = o.v;
    } else {
        // ---- params MLP, wave-parallel fp64. One wave per position.
        int wave = t >> 6, lane = t & 63;
        int p = (bid - 720) * 4 + wave;           // 0..2303
        int iy = p / WW, ix = p % WW;
        float ryf = (float)iy / 47.0f;
        float rxf = (float)ix / 47.0f;
        double ry = (double)ryf, rx = (double)rxf;

        double h[8];
        #pragma unroll
        for (int jj = 0; jj < 8; jj++) {
            int j = lane*8 + jj;
            double v = ry * (double)W1[j*2+0] + rx * (double)W1[j*2+1] + (double)b1[j];
            h[jj] = v > 0.0 ? v : 0.0;
        }
        double par[27];
        #pragma unroll
        for (int o = 0; o < 27; o++) {
            const float4* w4 = (const float4*)(W2 + (size_t)o*512 + lane*8);
            float4 wa = w4[0], wb = w4[1];
            double s = (double)wa.x*h[0] + (double)wa.y*h[1]
                     + (double)wa.z*h[2] + (double)wa.w*h[3]
                     + (double)wb.x*h[4] + (double)wb.y*h[5]
                     + (double)wb.z*h[6] + (double)wb.w*h[7];
            par[o] = s;
        }
        #pragma unroll
        for (int o = 0; o < 27; o++) {
            #pragma unroll
            for (int d = 1; d < 64; d <<= 1)
                par[o] += __shfl_xor(par[o], d, 64);
            par[o] += (double)b2[o];
        }
        if (lane < KK) {
            int k = lane;
            double scy = ry * 0.9999 + 5e-05;
            double scx = rx * 0.9999 + 5e-05;
            double midy = log(scy / (1.0 - scy));
            double midx = log(scx / (1.0 - scx));
            double zy = midy + 0.1 * par[2*k+0];
            double zx = midx + 0.1 * par[2*k+1];
            double my = 47.0 / (1.0 + exp(-zy));
            double mx = 47.0 / (1.0 + exp(-zx));
            double sr = par[18 + k] + 2.0;
            double sp = (sr > 0.0 ? sr : 0.0) + log1p(exp(-fabs(sr)));
            double sg = (sp + 0.05) * 48.0 * 0.05;
            means[(p*KK + k)*2 + 0] = (float)my;
            means[(p*KK + k)*2 + 1] = (float)mx;
            sigmas[p*KK + k] = (float)sg;
            fls[(p*KK + k)*2 + 0] = (int)floor(my);
            fls[(p*KK + k)*2 + 1] = (int)floor(mx);
        }
    }
}

// ---------------------------------------------------------------------------
// FUSED gather + GEMM (R13 = R9 best-measured + micro-tweaks):
// (512,4), MT=32, light barriers, XCD swizzle, packed 4B taps.
// Tweaks: int4 gints/roff setup loads; Bf(0) issued BEFORE setup math
// (asm memory clobber pins the loads above the barrier -> setup VALU
// covers their L2 latency).
// ---------------------------------------------------------------------------
__global__ __launch_bounds__(512, 4) void fused_kernel(
    const float* __restrict__ means, const float* __restrict__ sigmas,
    const int* __restrict__ fls, const int* __restrict__ gints,
    const int* __restrict__ roff, const short* __restrict__ xT,
    const bf16x8_t* __restrict__ Bp, const float* __restrict__ bu,
    float* __restrict__ out)
{
    __shared__ unsigned int s_tap[KK*MT*8];              // 9216 B
    __shared__ __align__(16) short s_feat[2][MT*SFP];    // 17408 B

    int t = threadIdx.x;
    // XCD swizzle: each XCD streams one batch image (~L2-resident; R10
    // measured FETCH 31->8.9 MB with this).
    int b   = blockIdx.x & 7;
    int grp = blockIdx.x >> 3;          // 0..71 within batch
    int ij0 = grp * MT;
    int m0  = b * HW + ij0;

    int lane = t & 63, wave = t >> 6;
    int r = lane & 31, q = lane >> 5;

    // ---- prologue: issue Bf(0) loads BEFORE setup; consumed at chunk 0 MFMA.
    bf16x8_t Bf0[8];
    {
        int base = (wave*72 + 0)*64 + lane;
        #pragma unroll
        for (int si = 0; si < 8; si++) Bf0[si] = Bp[base + si*64];
    }

    // ---- setup: taps + dup-kill + normalized weights for all (row,k)
    if (t < KK*MT) {
        int p = t;
        int k = p >> 5, row = p & 31;
        int ij = ij0 + row;
        int bij = m0 + row;
        int fy = fls[(ij*KK + k)*2 + 0];
        int fx = fls[(ij*KK + k)*2 + 1];
        float my = means[(ij*KK + k)*2 + 0];
        float mx = means[(ij*KK + k)*2 + 1];
        float sg = sigmas[ij*KK + k];
        // vectorized scattered reads: gints/roff (bij,k,·,2) -> int4
        int4 gi = *(const int4*)(gints + (size_t)(bij*KK + k)*4);
        int4 ro = *(const int4*)(roff  + (size_t)(bij*KK + k)*4);
        int lins[8]; float ws[8];
        #pragma unroll
        for (int v = 0; v < 8; v++) {
            int iy, ix;
            if (v < 4) {
                iy = fy + (v >> 1); ix = fx + (v & 1);
            } else if (v == 4) { iy = gi.x; ix = gi.y; }
            else if (v == 5)   { iy = gi.z; ix = gi.w; }
            else if (v == 6)   { iy = fy + ro.x - 6; ix = fx + ro.y - 6; }
            else               { iy = fy + ro.z - 6; ix = fx + ro.w - 6; }
            iy = ((iy % HH) + HH) % HH;
            ix = ((ix % WW) + WW) % WW;
            lins[v] = iy * WW + ix;
            float dy = ((float)iy - my) / sg;
            float dx = ((float)ix - mx) / sg;
            ws[v] = expf(-0.5f * (dy*dy + dx*dx));
        }
        #pragma unroll
        for (int v = 1; v < 8; v++) {
            bool dup = false;
            #pragma unroll
            for (int u = 0; u < 8; u++) if (u < v) dup = dup || (lins[u] == lins[v]);
            if (dup) ws[v] = 0.0f;
        }
        float sum = 0.0f;
        #pragma unroll
        for (int v = 0; v < 8; v++) sum += ws[v];
        float inv = 1.0f / sum;
        #pragma unroll
        for (int v = 0; v < 8; v++) {
            unsigned short hb = __half_as_ushort(__float2half(ws[v] * inv));
            s_tap[p*8+v] = ((unsigned int)lins[v] << 16) | (unsigned int)hb;
        }
    }
    LIGHT_BARRIER();

    const short* xb = xT + (size_t)b * (HW * CIN);
    int grow = t >> 4, gc0 = (t & 15) << 3;   // gather: row (0..31), 8-ch base

    f32x16_t acc = {};

    for (int k = 0; k < KK; k++) {
        // a) load tap data for chunk k
        bf16x8_t tap[8];
        float    wgt[8];
        {
            const unsigned int* tp = &s_tap[(k*MT + grow)*8];
            #pragma unroll
            for (int v = 0; v < 8; v++) {
                unsigned int e = tp[v];
                wgt[v] = __half2float(__ushort_as_half((unsigned short)(e & 0xffffu)));
                tap[v] = *(const bf16x8_t*)(xb + (size_t)(e >> 16) * CIN + gc0);
            }
        }
        // b) gather math chunk k -> LDS
        {
            float a0[8];
            #pragma unroll
            for (int j = 0; j < 8; j++) a0[j] = 0.0f;
            #pragma unroll
            for (int v = 0; v < 8; v++) {
                float w = wgt[v]; bf16x8_t d8 = tap[v];
                #pragma unroll
                for (int j = 0; j < 8; j++) a0[j] += w * b2f(d8[j]);
            }
            union { bf16x8_t v8; __hip_bfloat16 hh[8]; } o;
            #pragma unroll
            for (int j = 0; j < 8; j++) o.hh[j] = __float2bfloat16(a0[j]);
            *(bf16x8_t*)(&s_feat[k & 1][grow*SFP + gc0]) = o.v8;
        }
        // c) LDS-only barrier (in-flight global loads stay in flight)
        LIGHT_BARRIER();
        // d) B-fragments + MFMA for chunk k (k=0 uses prologue Bf0)
        {
            const short* fb = s_feat[k & 1];
            if (k == 0) {
                #pragma unroll
                for (int si = 0; si < 8; si++) {
                    bf16x8_t a = *(const bf16x8_t*)(fb + r*SFP + si*16 + q*8);
                    acc = __builtin_amdgcn_mfma_f32_32x32x16_bf16(a, Bf0[si], acc, 0, 0, 0);
                }
            } else {
                int base = (wave*72 + k*8)*64 + lane;
                #pragma unroll
                for (int si = 0; si < 8; si++) {
                    bf16x8_t Bf = Bp[base + si*64];
                    bf16x8_t a = *(const bf16x8_t*)(fb + r*SFP + si*16 + q*8);
                    acc = __builtin_amdgcn_mfma_f32_32x32x16_bf16(a, Bf, acc, 0, 0, 0);
                }
            }
        }
        // buf (k+2)&1 == k&1 only rewritten after barrier(k+1): safe.
    }

    // ---- epilogue: C col = r (n), row = (reg&3)+8*(reg>>2)+4*q
    int n = wave*32 + r;
    float bv = bu[n];
    float* oc = out + ((size_t)b * COUT + n) * HW + ij0;
    #pragma unroll
    for (int g4 = 0; g4 < 4; g4++) {
        f32x4_t vv;
        vv[0] = acc[g4*4+0] + bv;
        vv[1] = acc[g4*4+1] + bv;
        vv[2] = acc[g4*4+2] + bv;
        vv[3] = acc[g4*4+3] + bv;
        *(f32x4_t*)(oc + g4*8 + q*4) = vv;
    }
}

// ---------------------------------------------------------------------------
extern "C" void kernel_launch(void* const* d_in, const int* in_sizes, int n_in,
                              void* d_out, int out_size, void* d_ws, size_t ws_size,
                              hipStream_t stream)
{
    const float* x   = (const float*)d_in[0];
    const float* W1  = (const float*)d_in[1];
    const float* b1  = (const float*)d_in[2];
    const float* W2  = (const float*)d_in[3];
    const float* b2  = (const float*)d_in[4];
    const float* Wu  = (const float*)d_in[5];
    const float* bu  = (const float*)d_in[6];
    const int* gints = (const int*)d_in[7];
    const int* roff  = (const int*)d_in[8];
    float* out = (float*)d_out;

    char* ws = (char*)d_ws;
    float* ws_means  = (float*)(ws + 0);                    // 2304*18 fp32
    float* ws_sigma  = (float*)(ws + 165888);               // 2304*9  fp32
    int*   ws_fl     = (int*  )(ws + 248832);               // 2304*18 int
    short* ws_xT     = (short*)(ws + 414720);               // 8*2304*128 bf16
    bf16x8_t* ws_bp  = (bf16x8_t*)(ws + 5133312);           // packed Wu bf16

    prep_kernel<<<1296, 256, 0, stream>>>(x, (__hip_bfloat16*)ws_xT, Wu, ws_bp,
                                          W1, b1, W2, b2,
                                          ws_means, ws_sigma, ws_fl);
    fused_kernel<<<MM/MT, 512, 0, stream>>>(ws_means, ws_sigma, ws_fl, gints, roff,
                                            ws_xT, ws_bp, bu, out);
}